// Round 4
// baseline (2495.662 us; speedup 1.0000x reference)
//
#include <hip/hip_runtime.h>
#include <hip/hip_fp16.h>

#define NODES 20000
#define NEDGE 600000
#define BATCH 128
#define ITERS 120
#define LEAK  0.01f
#define HALF_COLS 64          // batch split into 2 halves of 64 columns

// padded CSR capacity: each row rounds up to multiple of 8 (max +7/row)
#define NEDGE_PAD (NEDGE + 8 * NODES)

typedef unsigned int uint32;
typedef unsigned short ushort16;

// ---- bf16 helpers (RNE) ----
__device__ __forceinline__ uint32 rne_bf16_bits(float f) {
    uint32 u = __float_as_uint(f);
    u += 0x7fffu + ((u >> 16) & 1u);
    return u >> 16;
}
__device__ __forceinline__ float bf16_to_f32(uint32 bits) {
    return __uint_as_float(bits << 16);
}

// ---------------- preprocessing kernels ----------------

__global__ void zero_counts_kernel(int* counts, uint32* csr_edge) {
    int i = blockIdx.x * blockDim.x + threadIdx.x;
    if (i < NODES) counts[i] = 0;
    for (int j = i; j < NEDGE_PAD; j += gridDim.x * blockDim.x)
        csr_edge[j] = 0u;   // pad: src=0, w=+0.0 (fp16)
}

__global__ void count_kernel(const int* __restrict__ tgt, int* counts) {
    int e = blockIdx.x * blockDim.x + threadIdx.x;
    if (e < NEDGE) atomicAdd(&counts[tgt[e]], 1);
}

// single-block exclusive scan over 8-padded counts -> row_off (NODES+1), cursor copy
__global__ void scan_kernel(const int* __restrict__ counts, int* row_off, int* cursor) {
    __shared__ int sums[1024];
    const int CH = (NODES + 1023) / 1024;  // 20
    int tid = threadIdx.x;
    int base = tid * CH;
    int s = 0;
    for (int i = 0; i < CH; ++i) {
        int idx = base + i;
        if (idx < NODES) s += (counts[idx] + 7) & ~7;
    }
    sums[tid] = s;
    __syncthreads();
    for (int off = 1; off < 1024; off <<= 1) {
        int v = sums[tid];
        int add = (tid >= off) ? sums[tid - off] : 0;
        __syncthreads();
        sums[tid] = v + add;
        __syncthreads();
    }
    int running = (tid == 0) ? 0 : sums[tid - 1];
    for (int i = 0; i < CH; ++i) {
        int idx = base + i;
        if (idx < NODES) {
            row_off[idx] = running;
            cursor[idx]  = running;
            running += (counts[idx] + 7) & ~7;
        }
    }
    if (tid == 1023) row_off[NODES] = running;
}

// scatter edges into padded CSR; pack (fp16 weight << 16 | src) into one uint
__global__ void scatter_kernel(const int* __restrict__ tgt, const int* __restrict__ src,
                               const float* __restrict__ w,
                               int* cursor, uint32* csr_edge) {
    int e = blockIdx.x * blockDim.x + threadIdx.x;
    if (e < NEDGE) {
        int p = atomicAdd(&cursor[tgt[e]], 1);
        uint32 wb = (uint32)__half_as_ushort(__float2half_rn(w[e]));
        csr_edge[p] = (wb << 16) | (uint32)src[e];
    }
}

// bIn_h[t*64 + b'] = x[b][t] + bias[t]  with b = h*64+b'; halves contiguous:
// bIn = [half0: NODES*64 floats][half1: NODES*64 floats]
__global__ void init_bin_kernel(const float* __restrict__ x, const float* __restrict__ bias,
                                float* __restrict__ bIn) {
    __shared__ float tile[32][33];
    int tt = blockIdx.x * 32;
    int bb = blockIdx.y * 32;   // 0,32,64,96 -> half = bb>=64
    int tx = threadIdx.x, ty = threadIdx.y;
    for (int i = ty; i < 32; i += 8)
        tile[i][tx] = x[(bb + i) * NODES + tt + tx];
    __syncthreads();
    float* dst = bIn + (size_t)(bb >> 6) * NODES * HALF_COLS;
    int lb = bb & 63;           // 0 or 32
    for (int i = ty; i < 32; i += 8) {
        int t = tt + i;
        dst[t * HALF_COLS + lb + tx] = tile[tx][i] + bias[t];
    }
}

// xhat1 = bf16(leaky(bIn))  (absorbs iteration 1; xhat0 = 0); processes 2 at a time
__global__ void init_xhat_kernel(const float2* __restrict__ bIn2, uint32* __restrict__ xhat) {
    int idx = blockIdx.x * blockDim.x + threadIdx.x;   // over 2*NODES*64/2
    float2 v = bIn2[idx];
    float a = (v.x < 0.0f) ? LEAK * v.x : v.x;
    float b = (v.y < 0.0f) ? LEAK * v.y : v.y;
    xhat[idx] = (rne_bf16_bits(b) << 16) | rne_bf16_bits(a);
}

// ---------------- main iteration kernel ----------------
// one wave per (node, half); lane = one batch column of that half (bf16 bits in ushort).
// half pinned to XCD group via blockIdx%8 (XCD 0-3 -> half 0, 4-7 -> half 1) so each
// XCD's gather working set is one 2.56 MB half -> L2-resident.
// rows padded to multiples of 8 -> branch-free 8-edge chunks, 8 gathers in flight.
__global__ __launch_bounds__(256) void spmv_act_kernel(
        const ushort16* __restrict__ xin_all,   // [2][NODES][64] bf16 bits
        const float*    __restrict__ bIn_all,   // [2][NODES][64] fp32
        const uint32*   __restrict__ csr_edge, const int* __restrict__ row_off,
        ushort16*       __restrict__ xout_all) {
    int wave = threadIdx.x >> 6;
    int lane = threadIdx.x & 63;
    int blk  = blockIdx.x;
    int h    = (blk & 7) >> 2;                       // XCD group -> half
    int g    = (blk >> 3) * 4 + (blk & 3);           // 0..4999 within half
    int t    = __builtin_amdgcn_readfirstlane(g * 4 + wave);   // node id

    const ushort16* xin  = xin_all  + (size_t)h * NODES * HALF_COLS;
    const float*    bIn  = bIn_all  + (size_t)h * NODES * HALF_COLS;
    ushort16*       xout = xout_all + (size_t)h * NODES * HALF_COLS;

    float acc = bIn[t * HALF_COLS + lane];
    int beg = row_off[t];
    int end = row_off[t + 1];
    for (int e = beg; e < end; e += 8) {
        uint32 E[8];
        ushort16 U[8];
#pragma unroll
        for (int i = 0; i < 8; ++i) E[i] = csr_edge[e + i];
#pragma unroll
        for (int i = 0; i < 8; ++i)
            U[i] = xin[(E[i] & 0xFFFFu) * HALF_COLS + lane];
#pragma unroll
        for (int i = 0; i < 8; ++i) {
            float w = __half2float(__ushort_as_half((ushort16)(E[i] >> 16)));
            acc = fmaf(w, bf16_to_f32((uint32)U[i]), acc);
        }
    }
    float r = (acc < 0.0f) ? LEAK * acc : acc;
    xout[t * HALF_COLS + lane] = (ushort16)rne_bf16_bits(r);
}

// out[b][t] = f32(xhat_{b>>6}[t][b&63]), LDS-tiled over 32-node tiles
__global__ __launch_bounds__(256) void transpose_out_kernel(
        const ushort16* __restrict__ xin_all, float* __restrict__ out) {
    __shared__ ushort16 tile[2][32][66];   // row stride 66 ushorts -> conflict-free
    int tt = blockIdx.x * 32;
    int tid = threadIdx.x;
    // phase 1: coalesced read, 32 nodes x 64 ushorts per half
    {
        int u = tid & 63;
        int n0 = tid >> 6;           // 0..3
        for (int h = 0; h < 2; ++h) {
            const ushort16* xin = xin_all + (size_t)h * NODES * HALF_COLS;
            for (int n = n0; n < 32; n += 4)
                tile[h][n][u] = xin[(tt + n) * HALF_COLS + u];
        }
    }
    __syncthreads();
    // phase 2: write out[b][tt+tn], coalesced along tn
    {
        int tn = tid & 31;
        int b0 = tid >> 5;           // 0..7
        for (int b = b0; b < BATCH; b += 8) {
            ushort16 u = tile[b >> 6][tn][b & 63];
            out[(size_t)b * NODES + tt + tn] = bf16_to_f32((uint32)u);
        }
    }
}

// ---------------- launch ----------------

extern "C" void kernel_launch(void* const* d_in, const int* in_sizes, int n_in,
                              void* d_out, int out_size, void* d_ws, size_t ws_size,
                              hipStream_t stream) {
    const float* x        = (const float*)d_in[0];   // [BATCH, NODES]
    const float* weights  = (const float*)d_in[1];   // [NEDGE]
    const float* bias     = (const float*)d_in[2];   // [NODES]
    const int*   tgt      = (const int*)d_in[3];     // [NEDGE]
    const int*   src      = (const int*)d_in[4];     // [NEDGE]
    float* out = (float*)d_out;                      // [BATCH, NODES]

    char* ws = (char*)d_ws;
    size_t off = 0;
    float*    bIn      = (float*)   (ws + off); off += (size_t)2 * NODES * HALF_COLS * sizeof(float);
    ushort16* xA       = (ushort16*)(ws + off); off += (size_t)2 * NODES * HALF_COLS * sizeof(ushort16);
    ushort16* xB       = (ushort16*)(ws + off); off += (size_t)2 * NODES * HALF_COLS * sizeof(ushort16);
    uint32*   csr_edge = (uint32*)  (ws + off); off += (size_t)NEDGE_PAD * sizeof(uint32);
    int*      counts   = (int*)     (ws + off); off += (size_t)NODES * sizeof(int);
    int*      row_off  = (int*)     (ws + off); off += (size_t)(NODES + 1) * sizeof(int);
    int*      cursor   = (int*)     (ws + off); off += (size_t)NODES * sizeof(int);

    // --- build padded CSR (by target) ---
    zero_counts_kernel<<<(NODES + 255) / 256, 256, 0, stream>>>(counts, csr_edge);
    count_kernel<<<(NEDGE + 255) / 256, 256, 0, stream>>>(tgt, counts);
    scan_kernel<<<1, 1024, 0, stream>>>(counts, row_off, cursor);
    scatter_kernel<<<(NEDGE + 255) / 256, 256, 0, stream>>>(tgt, src, weights,
                                                            cursor, csr_edge);

    // --- bIn + first iteration ---
    init_bin_kernel<<<dim3(NODES / 32, BATCH / 32), dim3(32, 8), 0, stream>>>(x, bias, bIn);
    init_xhat_kernel<<<2 * NODES * HALF_COLS / 2 / 256, 256, 0, stream>>>(
        (const float2*)bIn, (uint32*)xA);

    // --- remaining 119 iterations, ping-pong ---
    ushort16* cur = xA;
    ushort16* nxt = xB;
    for (int it = 1; it < ITERS; ++it) {
        spmv_act_kernel<<<NODES / 4 * 2, 256, 0, stream>>>(
            cur, bIn, csr_edge, row_off, nxt);
        ushort16* tmp = cur; cur = nxt; nxt = tmp;
    }

    // --- transpose to [BATCH, NODES] fp32 ---
    transpose_out_kernel<<<NODES / 32, 256, 0, stream>>>(cur, out);
}